// Round 15
// baseline (129.498 us; speedup 1.0000x reference)
//
#include <hip/hip_runtime.h>
#include <hip/hip_bf16.h>

typedef unsigned int u32;
typedef unsigned short u16;
typedef float f32x2 __attribute__((ext_vector_type(2)));
typedef float f32x4 __attribute__((ext_vector_type(4)));
using bf16x8 = __attribute__((ext_vector_type(8))) short;   // MFMA A/B frag (4 VGPRs)
using f32x4v = __attribute__((ext_vector_type(4))) float;   // MFMA C/D frag

#define DEVINL __device__ __forceinline__

// Problem constants: B=8, C=64, D=128, H=128, W=128
constexpr int XLDS = 16384;            // k_x: FT [128 w][128B] swz
constexpr int SCAN_LDS = 32768;        // k_scan: bufA(16K)+bufB(16K)
constexpr int XS = 132;                // k_final transpose staging stride (u16)
constexpr int LDS_X = 128 * XS * 2;    // 33792

DEVINL float bf2f(u16 u) { union { u32 i; float f; } v; v.i = ((u32)u) << 16; return v.f; }
DEVINL float bf2f_lo(u32 u) { union { u32 i; float f; } v; v.i = u << 16; return v.f; }
DEVINL float bf2f_hi(u32 u) { union { u32 i; float f; } v; v.i = u & 0xffff0000u; return v.f; }
DEVINL u16 f2bf(float f) {
  __hip_bfloat16 h = __float2bfloat16(f);
  u16 r; __builtin_memcpy(&r, &h, 2); return r;
}
DEVINL u32 pack2(float a, float b) { return (u32)f2bf(a) | ((u32)f2bf(b) << 16); }

// ---------------- P0: A=tanh(A_param), Mrow[dir][c][d] bf16, beff, Wi_bf ----------------
__global__ __launch_bounds__(256) void k_pre(
    const float* __restrict__ Wf, const float* __restrict__ Wo,
    const float* __restrict__ bf_, const float* __restrict__ bo,
    const float* __restrict__ A_param, const float* __restrict__ Wi,
    float* __restrict__ A_t, float* __restrict__ beff,
    u16* __restrict__ Mrow, u16* __restrict__ Wi_bf) {
  const int wg = blockIdx.x, t = threadIdx.x;
  if (wg < 128) {
    const int idx = wg * 256 + t;          // 0..32767
    const int cout = idx >> 9;             // 0..63
    const int k = idx & 511;               // dir*128 + d
    float s = 0.f;
    for (int d = 0; d < 128; ++d) s = fmaf(Wo[cout * 128 + d], Wf[d * 512 + k], s);
    const int dir = k >> 7, dm = k & 127;
    Mrow[(dir * 64 + cout) * 128 + dm] = f2bf(s);
  } else if (wg == 128) {
    if (t < 128) A_t[t] = tanhf(A_param[t]);
    if (t < 64) {
      float s = bo[t];
      for (int d = 0; d < 128; ++d) s = fmaf(Wo[t * 128 + d], bf_[d], s);
      beff[t] = s;
    }
  } else {
    // Wi[128 d][64 c] f32 -> bf16, same layout
#pragma unroll
    for (int k = 0; k < 32; ++k) {
      const int i = t + k * 256;
      Wi_bf[i] = f2bf(Wi[i]);
    }
  }
}

extern __shared__ char smem[];

// ---------------- K_X: x2[b][h][w][d] = B_d * (Wi @ Fmod + bi)  (pre-scaled) ----------------
__global__ __launch_bounds__(256, 4) void k_x(
    const float* __restrict__ F_in, const float* __restrict__ prior,
    const u16* __restrict__ Wi_bf, const float* __restrict__ bi,
    const float* __restrict__ Bp, const float* __restrict__ alpha_p,
    u16* __restrict__ x2) {
  char* FT = smem;   // [128 w][128B] swz

  const int t = threadIdx.x;
  const int lane = t & 63, wv = t >> 6, l15 = lane & 15, kg = lane >> 4;
  const int bid = blockIdx.x, b = bid >> 7, h = bid & 127;

  // ---- P1: stage Fmod^T bf16: row w = 64 c (128B), swz byte^((w&7)<<4) ----
  {
    const int w = t & 127, ch = t >> 7;
    const float alpha = alpha_p[0];
    const float pv = prior[(b * 128 + h) * 128 + w];
    const float* Fb = F_in + ((size_t)b * 64 + ch * 32) * 16384 + h * 128 + w;
    const u32 sw = (u32)((w & 7) << 4);
    char* rowp = FT + w * 128;
#pragma unroll
    for (int q = 0; q < 4; ++q) {
      float fv[8];
#pragma unroll
      for (int j = 0; j < 8; ++j) fv[j] = fmaf(alpha, pv, Fb[(q * 8 + j) * 16384]);
      uint4 pk;
      pk.x = pack2(fv[0], fv[1]); pk.y = pack2(fv[2], fv[3]);
      pk.z = pack2(fv[4], fv[5]); pk.w = pack2(fv[6], fv[7]);
      *(uint4*)(rowp + ((u32)(ch * 64 + q * 16) ^ sw)) = pk;
    }
  }
  __syncthreads();

  // ---- P2: Fmod B-frags into regs ----
  bf16x8 bF[2][2];   // [wj][ks]
#pragma unroll
  for (int wj = 0; wj < 2; ++wj)
#pragma unroll
    for (int ks = 0; ks < 2; ++ks) {
      const int row = wv * 32 + wj * 16 + l15;
      bF[wj][ks] = *(const bf16x8*)(FT + row * 128 + ((u32)(ks * 64 + kg * 16) ^ ((u32)((row & 7) << 4))));
    }

  // ---- P3: GEMM D[d][w] full 128 d; scale by B_d; x -> global (d-contiguous uint2) ----
  {
    f32x4v acc[8][2];   // [dt][wj]
#pragma unroll
    for (int dt = 0; dt < 8; ++dt) {
      const f32x4 bv = *(const f32x4*)(bi + dt * 16 + kg * 4);
      const f32x4v bvv = { bv.x, bv.y, bv.z, bv.w };
#pragma unroll
      for (int wj = 0; wj < 2; ++wj) acc[dt][wj] = bvv;
    }
#pragma unroll
    for (int ks = 0; ks < 2; ++ks)
#pragma unroll
      for (int dt = 0; dt < 8; ++dt) {
        const bf16x8 aWi = *(const bf16x8*)(Wi_bf + (dt * 16 + l15) * 64 + ks * 32 + kg * 8);
        acc[dt][0] = __builtin_amdgcn_mfma_f32_16x16x32_bf16(aWi, bF[0][ks], acc[dt][0], 0, 0, 0);
        acc[dt][1] = __builtin_amdgcn_mfma_f32_16x16x32_bf16(aWi, bF[1][ks], acc[dt][1], 0, 0, 0);
      }
    u16* xg = x2 + (size_t)(b * 128 + h) * 16384;   // [w][128 d]
#pragma unroll
    for (int dt = 0; dt < 8; ++dt) {
      const f32x4 B4 = *(const f32x4*)(Bp + dt * 16 + kg * 4);
      const f32x4v B4v = { B4.x, B4.y, B4.z, B4.w };
#pragma unroll
      for (int wj = 0; wj < 2; ++wj) {
        const f32x4v sv = acc[dt][wj] * B4v;   // pre-scale by B_d
        const int w = wv * 32 + wj * 16 + l15;
        const int dl = dt * 16 + kg * 4;
        uint2 pk;
        pk.x = pack2(sv[0], sv[1]);
        pk.y = pack2(sv[2], sv[3]);
        *(uint2*)(xg + w * 128 + dl) = pk;
      }
    }
  }
}

// ---- Single-pass serial scan of a d-pair column (u32 = 2 bf16), prefetch 8, swizzled. ----
// Input buf holds B*x; h = A*h + xv per step.
template <bool REV>
DEVINL void scan_serial(char* buf, int dp, f32x2 A2) {
  f32x2 h = { 0.f, 0.f };
  const u32 cb = (u32)(dp * 4);
  u32 nx[8];
#pragma unroll
  for (int j = 0; j < 8; ++j) {
    const int i = REV ? (127 - j) : j;
    nx[j] = *(const u32*)(buf + i * 128 + (cb ^ ((u32)((i & 7) << 4))));
  }
  for (int ib = 0; ib < 128; ib += 8) {
    u32 cur[8];
#pragma unroll
    for (int j = 0; j < 8; ++j) cur[j] = nx[j];
    if (ib + 8 < 128) {
#pragma unroll
      for (int j = 0; j < 8; ++j) {
        const int i2 = ib + 8 + j;
        const int i = REV ? (127 - i2) : i2;
        nx[j] = *(const u32*)(buf + i * 128 + (cb ^ ((u32)((i & 7) << 4))));
      }
    }
#pragma unroll
    for (int j = 0; j < 8; ++j) {
      const int i2 = ib + j;
      const int i = REV ? (127 - i2) : i2;
      const f32x2 xv = { bf2f_lo(cur[j]), bf2f_hi(cur[j]) };
      h = A2 * h + xv;                            // single v_pk_fma
      *(u32*)(buf + i * 128 + (cb ^ ((u32)((i & 7) << 4)))) = pack2(h.x, h.y);
    }
  }
}

// Both scans: one wave (t<64): dp = t&31, dir = t>>5. Each element touched ONCE.
DEVINL void run_scans(char* bufA, char* bufB, int t, int e, const float* __restrict__ A_t) {
  if (t < 64) {
    const int dp = t & 31, dir = t >> 5;
    const f32x2 a = *(const f32x2*)(A_t + e * 64 + dp * 2);
    if (dir == 0) scan_serial<false>(bufA, dp, a);
    else          scan_serial<true >(bufB, dp, a);
  }
}

// acc2 += h @ M[dir] in D[pos][c] orientation (h as A-operand, M as B-operand).
DEVINL void combine64(const char* buf, const u16* __restrict__ Mrow, int dir, int e,
                      int lane, int wv, f32x4v (&acc2)[4][2]) {
  const int l15 = lane & 15, kg = lane >> 4;
#pragma unroll
  for (int ks = 0; ks < 2; ++ks) {
    bf16x8 afr[4], bfr[2];
#pragma unroll
    for (int ct = 0; ct < 4; ++ct)
      afr[ct] = *(const bf16x8*)(Mrow + ((size_t)dir * 64 + ct * 16 + l15) * 128 + e * 64 + ks * 32 + kg * 8);
#pragma unroll
    for (int pt = 0; pt < 2; ++pt) {
      const int row = wv * 32 + pt * 16 + l15;
      bfr[pt] = *(const bf16x8*)(buf + row * 128 + ((u32)(ks * 64 + kg * 16) ^ ((u32)((row & 7) << 4))));
    }
#pragma unroll
    for (int ct = 0; ct < 4; ++ct)
#pragma unroll
      for (int pt = 0; pt < 2; ++pt)
        acc2[ct][pt] = __builtin_amdgcn_mfma_f32_16x16x32_bf16(bfr[pt], afr[ct], acc2[ct][pt], 0, 0, 0);
  }
}

// Store combine acc into smem as f32 [64 c][512B swz rows]; thread's f32x4 is pos-contiguous.
DEVINL void acc_to_outs(const f32x4v (&acc2)[4][2], int lane, int wv, char* buf) {
  const int l15 = lane & 15, kg = lane >> 4;
#pragma unroll
  for (int ct = 0; ct < 4; ++ct)
#pragma unroll
    for (int pt = 0; pt < 2; ++pt) {
      const int c = ct * 16 + l15;
      const int pos = wv * 32 + pt * 16 + kg * 4;
      *(f32x4v*)(buf + c * 512 + ((u32)(pos * 4) ^ ((u32)((c & 7) << 4)))) = acc2[ct][pt];
    }
}

// Epilogue: OutS -> partial [64 c][128 pos] bf16 stream (16 KB).
DEVINL void outs_to_global(const char* buf, u16* __restrict__ og, int t) {
#pragma unroll
  for (int j = 0; j < 16; ++j) {
    const int i = t + j * 256;
    const int c = i >> 6, p2 = (i & 63) * 2;
    const f32x2 v = *(const f32x2*)(buf + c * 512 + ((u32)(p2 * 4) ^ ((u32)((c & 7) << 4))));
    *(u32*)(og + c * 128 + p2) = pack2(v.x, v.y);
  }
}

// ---------------- K_SCAN: h- and v-scans interleaved in one kernel ----------------
// bid: kind = bid&1 (0=h, 1=v), bid2 = bid>>1 = ((b*128)+p)*2+e.
__global__ __launch_bounds__(256, 5) void k_scan(
    const u16* __restrict__ x2,
    const float* __restrict__ A_t, const u16* __restrict__ Mrow,
    u16* __restrict__ Shp, u16* __restrict__ Svp) {
  char* bufA = smem;
  char* bufB = smem + 16384;
  const int t = threadIdx.x;
  const int lane = t & 63, wv = t >> 6;
  const int bid = blockIdx.x;
  const int vert = bid & 1;
  const int bid2 = bid >> 1;
  const int b = bid2 >> 8, p = (bid2 >> 1) & 127, e = bid2 & 1;

  // ---- P1: stage B*x e-half rows into both buffers (128B granules) ----
#pragma unroll
  for (int j = 0; j < 4; ++j) {
    const int idx = t + j * 256;
    const int row = idx >> 3, q = idx & 7;
    const u16* src = vert
        ? x2 + (size_t)(b * 128 + row) * 16384 + p * 128 + e * 64 + q * 8
        : x2 + (size_t)(b * 128 + p) * 16384 + row * 128 + e * 64 + q * 8;
    const uint4 v = *(const uint4*)src;
    const u32 col = (u32)(q * 16) ^ ((u32)((row & 7) << 4));
    *(uint4*)(bufA + row * 128 + col) = v;
    *(uint4*)(bufB + row * 128 + col) = v;
  }
  __syncthreads();

  // ---- P2: single-pass serial scans (one wave; each element once) ----
  run_scans(bufA, bufB, t, e, A_t);
  __syncthreads();

  // ---- P3: combine both dirs ----
  f32x4v acc2[4][2];
#pragma unroll
  for (int i = 0; i < 4; ++i)
#pragma unroll
    for (int j = 0; j < 2; ++j) acc2[i][j] = (f32x4v)0.f;
  combine64(bufA, Mrow, vert ? 2 : 0, e, lane, wv, acc2);
  combine64(bufB, Mrow, vert ? 3 : 1, e, lane, wv, acc2);
  __syncthreads();

  // ---- P4: acc -> OutS ----
  acc_to_outs(acc2, lane, wv, smem);
  __syncthreads();

  // ---- P5: 16 KB stream out ----
  u16* og = (vert ? Svp : Shp) + (size_t)bid2 * 8192;
  outs_to_global(smem, og, t);
}

// ---------------- F: out = F_mod + gamma*(Sh0+Sh1 + (Sv0+Sv1)^T + beff) ----------------
__global__ __launch_bounds__(256) void k_final(
    const float* __restrict__ F_in, const float* __restrict__ prior,
    const float* __restrict__ alpha_p, const float* __restrict__ gamma_p,
    const float* __restrict__ beff, const u16* __restrict__ Svp,
    const u16* __restrict__ Shp, float* __restrict__ out) {
  u16* Xu = (u16*)smem;
  const int t = threadIdx.x;
  const int bid = blockIdx.x, b = bid >> 6, c = bid & 63;
  const size_t base = (size_t)bid * 16384;   // (b,c) plane of out/F

  // stage Sv = Svp(e0)+Svp(e1), transposed via LDS: Xu[w][h], stride 132
  for (int i = t; i < 2048; i += 256) {
    const int w = i >> 4, q = i & 15;
    const u16* s0 = Svp + ((size_t)((b * 128 + w) * 2)) * 8192 + c * 128 + q * 8;
    const uint4 a4 = *(const uint4*)(s0);
    const uint4 b4 = *(const uint4*)(s0 + 8192);
    const u16* ap = (const u16*)&a4;
    const u16* bp = (const u16*)&b4;
    u32* dst = (u32*)(Xu + w * 132 + q * 8);
#pragma unroll
    for (int k = 0; k < 4; ++k) {
      const float lo = bf2f(ap[k * 2]) + bf2f(bp[k * 2]);
      const float hi = bf2f(ap[k * 2 + 1]) + bf2f(bp[k * 2 + 1]);
      dst[k] = pack2(lo, hi);
    }
  }
  __syncthreads();
  const float alpha = alpha_p[0], gamma = gamma_p[0];
  const float be = beff[c];
  for (int i = t; i < 2048; i += 256) {
    const int hh = i >> 4, w8 = (i & 15) * 8;
    const size_t off = base + hh * 128 + w8;
    const u16* sh0 = Shp + ((size_t)((b * 128 + hh) * 2)) * 8192 + c * 128 + w8;
    const uint4 g0 = *(const uint4*)(sh0);
    const uint4 g1 = *(const uint4*)(sh0 + 8192);
    const u16* p0 = (const u16*)&g0;
    const u16* p1 = (const u16*)&g1;
    const float* Fp = F_in + off;
    float* Op = out + off;
    const float* Pp = prior + (b * 128 + hh) * 128 + w8;
#pragma unroll
    for (int q = 0; q < 8; ++q) {
      const float sv = bf2f(Xu[(w8 + q) * 132 + hh]);
      Op[q] = Fp[q] + alpha * Pp[q] + gamma * (bf2f(p0[q]) + bf2f(p1[q]) + sv + be);
    }
  }
}

extern "C" void kernel_launch(void* const* d_in, const int* in_sizes, int n_in,
                              void* d_out, int out_size, void* d_ws, size_t ws_size,
                              hipStream_t stream) {
  const float* F_in   = (const float*)d_in[0];
  const float* prior  = (const float*)d_in[1];
  const float* Wi     = (const float*)d_in[2];
  const float* bi     = (const float*)d_in[3];
  const float* A_par  = (const float*)d_in[4];
  const float* B_par  = (const float*)d_in[5];
  const float* alpha  = (const float*)d_in[6];
  const float* gamma  = (const float*)d_in[7];
  const float* Wf     = (const float*)d_in[8];
  const float* bf_    = (const float*)d_in[9];
  const float* Wo     = (const float*)d_in[10];
  const float* bo     = (const float*)d_in[11];
  float* out = (float*)d_out;

  char* ws = (char*)d_ws;
  float* A_t   = (float*)ws;                        // 512 B
  float* beff  = (float*)(ws + 512);                // 256 B
  u16*   Mrow  = (u16*)(ws + 1024);                 // 64 KB: [4][64][128] bf16
  u16*   Wi_bf = (u16*)(ws + 66560);                // 16 KB: [128][64] bf16
  u16*   x2    = (u16*)(ws + 82944);                // 33.5 MB: [1024][128 w][128 d] (B-prescaled)
  u16*   Shp   = (u16*)(ws + 82944 + 33554432);     // 33.5 MB: [2048][64 c][128 w]
  u16*   Svp   = (u16*)(ws + 82944 + 67108864);     // 33.5 MB: [2048][64 c][128 h]

  hipFuncSetAttribute((const void*)k_x,    hipFuncAttributeMaxDynamicSharedMemorySize, XLDS);
  hipFuncSetAttribute((const void*)k_scan, hipFuncAttributeMaxDynamicSharedMemorySize, SCAN_LDS);

  k_pre  <<<130, 256, 0, stream>>>(Wf, Wo, bf_, bo, A_par, Wi, A_t, beff, Mrow, Wi_bf);
  k_x    <<<1024, 256, XLDS, stream>>>(F_in, prior, Wi_bf, bi, B_par, alpha, x2);
  k_scan <<<4096, 256, SCAN_LDS, stream>>>(x2, A_t, Mrow, Shp, Svp);
  k_final<<<512, 256, LDS_X, stream>>>(F_in, prior, alpha, gamma, beff, Svp, Shp, out);
}

// Round 16
// 100.763 us; speedup vs baseline: 1.2852x; 1.2852x over previous
//
#include <hip/hip_runtime.h>
#include <hip/hip_bf16.h>

typedef unsigned int u32;
typedef unsigned short u16;
typedef float f32x2 __attribute__((ext_vector_type(2)));
typedef float f32x4 __attribute__((ext_vector_type(4)));
using bf16x8 = __attribute__((ext_vector_type(8))) short;   // MFMA A/B frag (4 VGPRs)
using f32x4v = __attribute__((ext_vector_type(4))) float;   // MFMA C/D frag

#define DEVINL __device__ __forceinline__

// Problem constants: B=8, C=64, D=128, H=128, W=128
// d-split: each k_A/k_B block handles 64 channels (e = 0 or 1).
constexpr int SCAN_LDS = 32768;        // bufA(16K) + bufB(16K)
constexpr int XS = 132;                // k_final transpose staging stride (u16)
constexpr int LDS_X = 128 * XS * 2;    // 33792

DEVINL float bf2f(u16 u) { union { u32 i; float f; } v; v.i = ((u32)u) << 16; return v.f; }
DEVINL float bf2f_lo(u32 u) { union { u32 i; float f; } v; v.i = u << 16; return v.f; }
DEVINL float bf2f_hi(u32 u) { union { u32 i; float f; } v; v.i = u & 0xffff0000u; return v.f; }
DEVINL u16 f2bf(float f) {
  __hip_bfloat16 h = __float2bfloat16(f);
  u16 r; __builtin_memcpy(&r, &h, 2); return r;
}
DEVINL u32 pack2(float a, float b) { return (u32)f2bf(a) | ((u32)f2bf(b) << 16); }

// ---------------- P0: A=tanh(A_param), Mrow[dir][c][d] bf16, beff, Wi_bf ----------------
__global__ __launch_bounds__(256) void k_pre(
    const float* __restrict__ Wf, const float* __restrict__ Wo,
    const float* __restrict__ bf_, const float* __restrict__ bo,
    const float* __restrict__ A_param, const float* __restrict__ Wi,
    float* __restrict__ A_t, float* __restrict__ beff,
    u16* __restrict__ Mrow, u16* __restrict__ Wi_bf) {
  const int wg = blockIdx.x, t = threadIdx.x;
  if (wg < 128) {
    const int idx = wg * 256 + t;          // 0..32767
    const int cout = idx >> 9;             // 0..63
    const int k = idx & 511;               // dir*128 + d
    float s = 0.f;
    for (int d = 0; d < 128; ++d) s = fmaf(Wo[cout * 128 + d], Wf[d * 512 + k], s);
    const int dir = k >> 7, dm = k & 127;
    Mrow[(dir * 64 + cout) * 128 + dm] = f2bf(s);
  } else if (wg == 128) {
    if (t < 128) A_t[t] = tanhf(A_param[t]);
    if (t < 64) {
      float s = bo[t];
      for (int d = 0; d < 128; ++d) s = fmaf(Wo[t * 128 + d], bf_[d], s);
      beff[t] = s;
    }
  } else {
    // Wi[128 d][64 c] f32 -> bf16, same layout
#pragma unroll
    for (int k = 0; k < 32; ++k) {
      const int i = t + k * 256;
      Wi_bf[i] = f2bf(Wi[i]);
    }
  }
}

extern __shared__ char smem[];

// ---- 8x16 chunked scan, 4 channels (u64) per thread. buf = [128 pos][128B] swz.
// Input holds B*x (pre-scaled); step h = A*h + xv.
template <bool REV>
DEVINL void scan16(char* buf, int dq, int chunk, f32x2 a01, f32x2 a23) {
  const u32 cb = (u32)(dq * 8);
  const int s = chunk * 16;
  uint2 v[16];
#pragma unroll
  for (int j = 0; j < 16; ++j) {
    const int i2 = s + j;
    const int i = REV ? (127 - i2) : i2;
    v[j] = *(const uint2*)(buf + i * 128 + (cb ^ ((u32)((i & 7) << 4))));
  }
  f32x2 h01 = { 0.f, 0.f }, h23 = { 0.f, 0.f };
#pragma unroll
  for (int j = 0; j < 16; ++j) {
    const f32x2 x0 = { bf2f_lo(v[j].x), bf2f_hi(v[j].x) };
    const f32x2 x1 = { bf2f_lo(v[j].y), bf2f_hi(v[j].y) };
    h01 = a01 * h01 + x0;
    h23 = a23 * h23 + x1;
    v[j].x = pack2(h01.x, h01.y);
    v[j].y = pack2(h23.x, h23.y);
  }
#pragma unroll
  for (int j = 0; j < 16; ++j) {
    const int i2 = s + j;
    const int i = REV ? (127 - i2) : i2;
    *(uint2*)(buf + i * 128 + (cb ^ ((u32)((i & 7) << 4)))) = v[j];
  }
}

// Carry fix: h_i = l_i + A^{j+1} * C, C folded from chunk-end rows (f32).
template <bool REV>
DEVINL void fix16(char* buf, int dq, int chunk, f32x2 a01, f32x2 a23) {
  if (chunk == 0) return;
  f32x2 q01 = a01, q23 = a23;
#pragma unroll
  for (int k = 0; k < 4; ++k) { q01 *= q01; q23 *= q23; }   // A^16
  const u32 cb = (u32)(dq * 8);
  f32x2 C01 = { 0.f, 0.f }, C23 = { 0.f, 0.f };
  for (int k = 0; k < chunk; ++k) {
    const int i2 = k * 16 + 15;
    const int i = REV ? (127 - i2) : i2;
    const uint2 v = *(const uint2*)(buf + i * 128 + (cb ^ ((u32)((i & 7) << 4))));
    C01 = C01 * q01 + (f32x2){ bf2f_lo(v.x), bf2f_hi(v.x) };
    C23 = C23 * q23 + (f32x2){ bf2f_lo(v.y), bf2f_hi(v.y) };
  }
  const int s = chunk * 16;
  uint2 v[16];
#pragma unroll
  for (int j = 0; j < 16; ++j) {
    const int i2 = s + j;
    const int i = REV ? (127 - i2) : i2;
    v[j] = *(const uint2*)(buf + i * 128 + (cb ^ ((u32)((i & 7) << 4))));
  }
  f32x2 p01 = a01, p23 = a23;
#pragma unroll
  for (int j = 0; j < 16; ++j) {
    const f32x2 h0 = p01 * C01 + (f32x2){ bf2f_lo(v[j].x), bf2f_hi(v[j].x) };
    const f32x2 h1 = p23 * C23 + (f32x2){ bf2f_lo(v[j].y), bf2f_hi(v[j].y) };
    v[j].x = pack2(h0.x, h0.y);
    v[j].y = pack2(h1.x, h1.y);
    p01 *= a01; p23 *= a23;
  }
#pragma unroll
  for (int j = 0; j < 16; ++j) {
    const int i2 = s + j;
    const int i = REV ? (127 - i2) : i2;
    *(uint2*)(buf + i * 128 + (cb ^ ((u32)((i & 7) << 4)))) = v[j];
  }
}

// Both scans: 256 threads = 16 dq x 8 chunks x 2 dirs. Dep chain = 16+16.
DEVINL void run_scans(char* bufA, char* bufB, int t, int e, const float* __restrict__ A_t) {
  const int dq = t & 15, chunk = (t >> 4) & 7, dir = t >> 7;
  const f32x2 a01 = *(const f32x2*)(A_t + e * 64 + dq * 4);
  const f32x2 a23 = *(const f32x2*)(A_t + e * 64 + dq * 4 + 2);
  char* sb = dir ? bufB : bufA;
  if (dir == 0) scan16<false>(sb, dq, chunk, a01, a23);
  else          scan16<true >(sb, dq, chunk, a01, a23);
  __syncthreads();
  if (dir == 0) fix16<false>(sb, dq, chunk, a01, a23);
  else          fix16<true >(sb, dq, chunk, a01, a23);
}

// acc2 += h @ M[dir] in D[pos][c] orientation (h as A-operand, M as B-operand).
DEVINL void combine64(const char* buf, const u16* __restrict__ Mrow, int dir, int e,
                      int lane, int wv, f32x4v (&acc2)[4][2]) {
  const int l15 = lane & 15, kg = lane >> 4;
#pragma unroll
  for (int ks = 0; ks < 2; ++ks) {
    bf16x8 afr[4], bfr[2];
#pragma unroll
    for (int ct = 0; ct < 4; ++ct)
      afr[ct] = *(const bf16x8*)(Mrow + ((size_t)dir * 64 + ct * 16 + l15) * 128 + e * 64 + ks * 32 + kg * 8);
#pragma unroll
    for (int pt = 0; pt < 2; ++pt) {
      const int row = wv * 32 + pt * 16 + l15;
      bfr[pt] = *(const bf16x8*)(buf + row * 128 + ((u32)(ks * 64 + kg * 16) ^ ((u32)((row & 7) << 4))));
    }
#pragma unroll
    for (int ct = 0; ct < 4; ++ct)
#pragma unroll
      for (int pt = 0; pt < 2; ++pt)
        acc2[ct][pt] = __builtin_amdgcn_mfma_f32_16x16x32_bf16(bfr[pt], afr[ct], acc2[ct][pt], 0, 0, 0);
  }
}

// Store combine acc into smem as f32 [64 c][512B swz rows]; thread's f32x4 is pos-contiguous.
DEVINL void acc_to_outs(const f32x4v (&acc2)[4][2], int lane, int wv, char* buf) {
  const int l15 = lane & 15, kg = lane >> 4;
#pragma unroll
  for (int ct = 0; ct < 4; ++ct)
#pragma unroll
    for (int pt = 0; pt < 2; ++pt) {
      const int c = ct * 16 + l15;
      const int pos = wv * 32 + pt * 16 + kg * 4;
      *(f32x4v*)(buf + c * 512 + ((u32)(pos * 4) ^ ((u32)((c & 7) << 4)))) = acc2[ct][pt];
    }
}

// Epilogue: OutS -> partial [64 c][128 pos] bf16 stream (16 KB).
DEVINL void outs_to_global(const char* buf, u16* __restrict__ og, int t) {
#pragma unroll
  for (int j = 0; j < 16; ++j) {
    const int i = t + j * 256;
    const int c = i >> 6, p2 = (i & 63) * 2;
    const f32x2 v = *(const f32x2*)(buf + c * 512 + ((u32)(p2 * 4) ^ ((u32)((c & 7) << 4))));
    *(u32*)(og + c * 128 + p2) = pack2(v.x, v.y);
  }
}

// ---------------- K_A: x-GEMM (64 d half) + horizontal scans + combine ----------------
// bid = ((b*128)+h)*2+e. Writes x2[bid][w][64] (B-prescaled) and Shp[bid][c][w].
__global__ __launch_bounds__(256, 5) void k_A(
    const float* __restrict__ F_in, const float* __restrict__ prior,
    const u16* __restrict__ Wi_bf, const float* __restrict__ bi,
    const float* __restrict__ Bp, const float* __restrict__ alpha_p,
    const float* __restrict__ A_t, const u16* __restrict__ Mrow,
    u16* __restrict__ x2, u16* __restrict__ Shp) {
  char* bufA = smem;            // 16 KB [128][128B] swz: FT -> Bx -> h_lr
  char* bufB = smem + 16384;    // 16 KB: Bx copy -> h_rl

  const int t = threadIdx.x;
  const int lane = t & 63, wv = t >> 6, l15 = lane & 15, kg = lane >> 4;
  const int bid = blockIdx.x;
  const int b = bid >> 8, h = (bid >> 1) & 127, e = bid & 1;

  // ---- P1: stage Fmod^T bf16 into bufA: row w = 64 c (128B), swz ----
  {
    const int w = t & 127, ch = t >> 7;
    const float alpha = alpha_p[0];
    const float pv = prior[(b * 128 + h) * 128 + w];
    const float* Fb = F_in + ((size_t)b * 64 + ch * 32) * 16384 + h * 128 + w;
    const u32 sw = (u32)((w & 7) << 4);
    char* rowp = bufA + w * 128;
#pragma unroll
    for (int q = 0; q < 4; ++q) {
      float fv[8];
#pragma unroll
      for (int j = 0; j < 8; ++j) fv[j] = fmaf(alpha, pv, Fb[(q * 8 + j) * 16384]);
      uint4 pk;
      pk.x = pack2(fv[0], fv[1]); pk.y = pack2(fv[2], fv[3]);
      pk.z = pack2(fv[4], fv[5]); pk.w = pack2(fv[6], fv[7]);
      *(uint4*)(rowp + ((u32)(ch * 64 + q * 16) ^ sw)) = pk;
    }
  }
  __syncthreads();

  // ---- P2: Fmod B-frags (n=w) into regs before bufA is overwritten ----
  bf16x8 bF[2][2];   // [wj][ks]
#pragma unroll
  for (int wj = 0; wj < 2; ++wj)
#pragma unroll
    for (int ks = 0; ks < 2; ++ks) {
      const int row = wv * 32 + wj * 16 + l15;
      bF[wj][ks] = *(const bf16x8*)(bufA + row * 128 + ((u32)(ks * 64 + kg * 16) ^ ((u32)((row & 7) << 4))));
    }
  __syncthreads();

  // ---- P3: GEMM D[d][w]; prescale by B_d; Bx -> bufA + bufB (8B swizzled) ----
  {
    f32x4v acc[4][2];   // [dt][wj]
#pragma unroll
    for (int dt = 0; dt < 4; ++dt) {
      const f32x4 bv = *(const f32x4*)(bi + e * 64 + dt * 16 + kg * 4);
      const f32x4v bvv = { bv.x, bv.y, bv.z, bv.w };
#pragma unroll
      for (int wj = 0; wj < 2; ++wj) acc[dt][wj] = bvv;
    }
#pragma unroll
    for (int ks = 0; ks < 2; ++ks)
#pragma unroll
      for (int dt = 0; dt < 4; ++dt) {
        const bf16x8 aWi = *(const bf16x8*)(Wi_bf + (e * 64 + dt * 16 + l15) * 64 + ks * 32 + kg * 8);
        acc[dt][0] = __builtin_amdgcn_mfma_f32_16x16x32_bf16(aWi, bF[0][ks], acc[dt][0], 0, 0, 0);
        acc[dt][1] = __builtin_amdgcn_mfma_f32_16x16x32_bf16(aWi, bF[1][ks], acc[dt][1], 0, 0, 0);
      }
#pragma unroll
    for (int dt = 0; dt < 4; ++dt) {
      const f32x4 B4 = *(const f32x4*)(Bp + e * 64 + dt * 16 + kg * 4);
      const f32x4v B4v = { B4.x, B4.y, B4.z, B4.w };
#pragma unroll
      for (int wj = 0; wj < 2; ++wj) {
        const f32x4v sv = acc[dt][wj] * B4v;
        const int w = wv * 32 + wj * 16 + l15;
        const int dl = dt * 16 + kg * 4;          // d_local base
        uint2 pk;
        pk.x = pack2(sv[0], sv[1]);
        pk.y = pack2(sv[2], sv[3]);
        const u32 col = (u32)(dl * 2) ^ ((u32)((w & 7) << 4));
        *(uint2*)(bufA + w * 128 + col) = pk;
        *(uint2*)(bufB + w * 128 + col) = pk;
      }
    }
  }
  __syncthreads();

  // ---- P4: Bx -> global x2 (16 KB coalesced stream from bufA) ----
  {
    u16* xg = x2 + (size_t)bid * 8192;
#pragma unroll
    for (int j = 0; j < 4; ++j) {
      const int idx = t + j * 256;
      const int row = idx >> 3, q = idx & 7;
      const uint4 v = *(const uint4*)(bufA + row * 128 + ((u32)(q * 16) ^ ((u32)((row & 7) << 4))));
      *(uint4*)(xg + row * 64 + q * 8) = v;
    }
  }
  __syncthreads();

  // ---- P5: 8x16 chunked scans (all 256 threads; internal barrier) ----
  run_scans(bufA, bufB, t, e, A_t);
  __syncthreads();

  // ---- P6: combine dir0 (bufA) + dir1 (bufB) ----
  f32x4v acc2[4][2];
#pragma unroll
  for (int i = 0; i < 4; ++i)
#pragma unroll
    for (int j = 0; j < 2; ++j) acc2[i][j] = (f32x4v)0.f;
  combine64(bufA, Mrow, 0, e, lane, wv, acc2);
  combine64(bufB, Mrow, 1, e, lane, wv, acc2);
  __syncthreads();

  // ---- P7: acc -> OutS (32 KB f32 spanning both buffers) ----
  acc_to_outs(acc2, lane, wv, smem);
  __syncthreads();

  // ---- P8: Shp[bid][c][w] (16 KB stream) ----
  outs_to_global(smem, Shp + (size_t)bid * 8192, t);
}

// ---------------- K_B: vertical scans + combine -> Svp[bid][c][h] ----------------
// bid = ((b*128)+w)*2+e.
__global__ __launch_bounds__(256, 5) void k_B(
    const u16* __restrict__ x2,
    const float* __restrict__ A_t, const u16* __restrict__ Mrow,
    u16* __restrict__ Svp) {
  char* bufA = smem;
  char* bufB = smem + 16384;
  const int t = threadIdx.x;
  const int lane = t & 63, wv = t >> 6;
  const int bid = blockIdx.x;
  const int b = bid >> 8, w = (bid >> 1) & 127, e = bid & 1;

  // ---- P1: stage Bx rows (h-major) into both buffers; 128B L3-hot segments ----
#pragma unroll
  for (int j = 0; j < 4; ++j) {
    const int idx = t + j * 256;
    const int hh = idx >> 3, q = idx & 7;
    const uint4 v = *(const uint4*)(x2 + ((size_t)((b * 128 + hh) * 2 + e)) * 8192 + w * 64 + q * 8);
    const u32 col = (u32)(q * 16) ^ ((u32)((hh & 7) << 4));
    *(uint4*)(bufA + hh * 128 + col) = v;
    *(uint4*)(bufB + hh * 128 + col) = v;
  }
  __syncthreads();

  // ---- P2: 8x16 chunked scans ----
  run_scans(bufA, bufB, t, e, A_t);
  __syncthreads();

  // ---- P3: combine dir2 (bufA) + dir3 (bufB) ----
  f32x4v acc2[4][2];
#pragma unroll
  for (int i = 0; i < 4; ++i)
#pragma unroll
    for (int j = 0; j < 2; ++j) acc2[i][j] = (f32x4v)0.f;
  combine64(bufA, Mrow, 2, e, lane, wv, acc2);
  combine64(bufB, Mrow, 3, e, lane, wv, acc2);
  __syncthreads();

  // ---- P4: acc -> OutS ----
  acc_to_outs(acc2, lane, wv, smem);
  __syncthreads();

  // ---- P5: Svp[bid][c][h] (16 KB stream) ----
  outs_to_global(smem, Svp + (size_t)bid * 8192, t);
}

// ---------------- F: out = F_mod + gamma*(Sh0+Sh1 + (Sv0+Sv1)^T + beff) ----------------
__global__ __launch_bounds__(256) void k_final(
    const float* __restrict__ F_in, const float* __restrict__ prior,
    const float* __restrict__ alpha_p, const float* __restrict__ gamma_p,
    const float* __restrict__ beff, const u16* __restrict__ Svp,
    const u16* __restrict__ Shp, float* __restrict__ out) {
  u16* Xu = (u16*)smem;
  const int t = threadIdx.x;
  const int bid = blockIdx.x, b = bid >> 6, c = bid & 63;
  const size_t base = (size_t)bid * 16384;   // (b,c) plane of out/F

  // stage Sv = Svp(e0)+Svp(e1), transposed via LDS: Xu[w][h], stride 132
  for (int i = t; i < 2048; i += 256) {
    const int w = i >> 4, q = i & 15;
    const u16* s0 = Svp + ((size_t)((b * 128 + w) * 2)) * 8192 + c * 128 + q * 8;
    const uint4 a4 = *(const uint4*)(s0);
    const uint4 b4 = *(const uint4*)(s0 + 8192);
    const u16* ap = (const u16*)&a4;
    const u16* bp = (const u16*)&b4;
    u32* dst = (u32*)(Xu + w * 132 + q * 8);
#pragma unroll
    for (int k = 0; k < 4; ++k) {
      const float lo = bf2f(ap[k * 2]) + bf2f(bp[k * 2]);
      const float hi = bf2f(ap[k * 2 + 1]) + bf2f(bp[k * 2 + 1]);
      dst[k] = pack2(lo, hi);
    }
  }
  __syncthreads();
  const float alpha = alpha_p[0], gamma = gamma_p[0];
  const float be = beff[c];
  for (int i = t; i < 2048; i += 256) {
    const int hh = i >> 4, w8 = (i & 15) * 8;
    const size_t off = base + hh * 128 + w8;
    const u16* sh0 = Shp + ((size_t)((b * 128 + hh) * 2)) * 8192 + c * 128 + w8;
    const uint4 g0 = *(const uint4*)(sh0);
    const uint4 g1 = *(const uint4*)(sh0 + 8192);
    const u16* p0 = (const u16*)&g0;
    const u16* p1 = (const u16*)&g1;
    const float* Fp = F_in + off;
    float* Op = out + off;
    const float* Pp = prior + (b * 128 + hh) * 128 + w8;
#pragma unroll
    for (int q = 0; q < 8; ++q) {
      const float sv = bf2f(Xu[(w8 + q) * 132 + hh]);
      Op[q] = Fp[q] + alpha * Pp[q] + gamma * (bf2f(p0[q]) + bf2f(p1[q]) + sv + be);
    }
  }
}

extern "C" void kernel_launch(void* const* d_in, const int* in_sizes, int n_in,
                              void* d_out, int out_size, void* d_ws, size_t ws_size,
                              hipStream_t stream) {
  const float* F_in   = (const float*)d_in[0];
  const float* prior  = (const float*)d_in[1];
  const float* Wi     = (const float*)d_in[2];
  const float* bi     = (const float*)d_in[3];
  const float* A_par  = (const float*)d_in[4];
  const float* B_par  = (const float*)d_in[5];
  const float* alpha  = (const float*)d_in[6];
  const float* gamma  = (const float*)d_in[7];
  const float* Wf     = (const float*)d_in[8];
  const float* bf_    = (const float*)d_in[9];
  const float* Wo     = (const float*)d_in[10];
  const float* bo     = (const float*)d_in[11];
  float* out = (float*)d_out;

  char* ws = (char*)d_ws;
  float* A_t   = (float*)ws;                        // 512 B
  float* beff  = (float*)(ws + 512);                // 256 B
  u16*   Mrow  = (u16*)(ws + 1024);                 // 64 KB: [4][64][128] bf16
  u16*   Wi_bf = (u16*)(ws + 66560);                // 16 KB: [128][64] bf16
  u16*   x2    = (u16*)(ws + 82944);                // 33.5 MB: [2048][128 w][64 d] (B-prescaled)
  u16*   Shp   = (u16*)(ws + 82944 + 33554432);     // 33.5 MB: [2048][64 c][128 w]
  u16*   Svp   = (u16*)(ws + 82944 + 67108864);     // 33.5 MB: [2048][64 c][128 h]

  hipFuncSetAttribute((const void*)k_A, hipFuncAttributeMaxDynamicSharedMemorySize, SCAN_LDS);
  hipFuncSetAttribute((const void*)k_B, hipFuncAttributeMaxDynamicSharedMemorySize, SCAN_LDS);

  k_pre  <<<130, 256, 0, stream>>>(Wf, Wo, bf_, bo, A_par, Wi, A_t, beff, Mrow, Wi_bf);
  k_A    <<<2048, 256, SCAN_LDS, stream>>>(F_in, prior, Wi_bf, bi, B_par, alpha, A_t, Mrow, x2, Shp);
  k_B    <<<2048, 256, SCAN_LDS, stream>>>(x2, A_t, Mrow, Svp);
  k_final<<<512, 256, LDS_X, stream>>>(F_in, prior, alpha, gamma, beff, Svp, Shp, out);
}

// Round 17
// 100.688 us; speedup vs baseline: 1.2861x; 1.0007x over previous
//
#include <hip/hip_runtime.h>
#include <hip/hip_bf16.h>

typedef unsigned int u32;
typedef unsigned short u16;
typedef float f32x2 __attribute__((ext_vector_type(2)));
typedef float f32x4 __attribute__((ext_vector_type(4)));
using bf16x8 = __attribute__((ext_vector_type(8))) short;   // MFMA A/B frag (4 VGPRs)
using f32x4v = __attribute__((ext_vector_type(4))) float;   // MFMA C/D frag

#define DEVINL __device__ __forceinline__

// Problem constants: B=8, C=64, D=128, H=128, W=128
// d-split: each k_A/k_B block handles 64 channels (e = 0 or 1).
constexpr int SCAN_LDS = 32768;        // bufA(16K) + bufB(16K)
constexpr int XS = 132;                // k_final transpose staging stride (u16)
constexpr int LDS_X = 128 * XS * 2;    // 33792

DEVINL float bf2f(u16 u) { union { u32 i; float f; } v; v.i = ((u32)u) << 16; return v.f; }
DEVINL float bf2f_lo(u32 u) { union { u32 i; float f; } v; v.i = u << 16; return v.f; }
DEVINL float bf2f_hi(u32 u) { union { u32 i; float f; } v; v.i = u & 0xffff0000u; return v.f; }
DEVINL u16 f2bf(float f) {
  __hip_bfloat16 h = __float2bfloat16(f);
  u16 r; __builtin_memcpy(&r, &h, 2); return r;
}
DEVINL u32 pack2(float a, float b) { return (u32)f2bf(a) | ((u32)f2bf(b) << 16); }

// lgkm-only barrier: LDS visibility without draining outstanding global stores.
DEVINL void barrier_lgkm() {
  asm volatile("s_waitcnt lgkmcnt(0)" ::: "memory");
  __builtin_amdgcn_s_barrier();
  __builtin_amdgcn_sched_barrier(0);
}

// ---------------- P0: A=tanh(A_param), Mrow[dir][c][d] bf16, beff, Wi_bf ----------------
__global__ __launch_bounds__(256) void k_pre(
    const float* __restrict__ Wf, const float* __restrict__ Wo,
    const float* __restrict__ bf_, const float* __restrict__ bo,
    const float* __restrict__ A_param, const float* __restrict__ Wi,
    float* __restrict__ A_t, float* __restrict__ beff,
    u16* __restrict__ Mrow, u16* __restrict__ Wi_bf) {
  const int wg = blockIdx.x, t = threadIdx.x;
  if (wg < 128) {
    const int idx = wg * 256 + t;          // 0..32767
    const int cout = idx >> 9;             // 0..63
    const int k = idx & 511;               // dir*128 + d
    float s = 0.f;
    for (int d = 0; d < 128; ++d) s = fmaf(Wo[cout * 128 + d], Wf[d * 512 + k], s);
    const int dir = k >> 7, dm = k & 127;
    Mrow[(dir * 64 + cout) * 128 + dm] = f2bf(s);
  } else if (wg == 128) {
    if (t < 128) A_t[t] = tanhf(A_param[t]);
    if (t < 64) {
      float s = bo[t];
      for (int d = 0; d < 128; ++d) s = fmaf(Wo[t * 128 + d], bf_[d], s);
      beff[t] = s;
    }
  } else {
    // Wi[128 d][64 c] f32 -> bf16, same layout
#pragma unroll
    for (int k = 0; k < 32; ++k) {
      const int i = t + k * 256;
      Wi_bf[i] = f2bf(Wi[i]);
    }
  }
}

extern __shared__ char smem[];

// ---- Chunked scan (4 chunks x 32), prescaled input (B*x): h = A*h + xv. ----
template <bool REV>
DEVINL void scan_local(char* buf, int dp, int chunk, f32x2 A2) {
  f32x2 h = { 0.f, 0.f };
  const u32 cb = (u32)(dp * 4);
  const int s = chunk * 32;
  u32 nx[8];
#pragma unroll
  for (int j = 0; j < 8; ++j) {
    const int i = REV ? (127 - (s + j)) : (s + j);
    nx[j] = *(const u32*)(buf + i * 128 + (cb ^ ((u32)((i & 7) << 4))));
  }
  for (int ib = 0; ib < 32; ib += 8) {
    u32 cur[8];
#pragma unroll
    for (int j = 0; j < 8; ++j) cur[j] = nx[j];
    if (ib + 8 < 32) {
#pragma unroll
      for (int j = 0; j < 8; ++j) {
        const int i2 = s + ib + 8 + j;
        const int i = REV ? (127 - i2) : i2;
        nx[j] = *(const u32*)(buf + i * 128 + (cb ^ ((u32)((i & 7) << 4))));
      }
    }
#pragma unroll
    for (int j = 0; j < 8; ++j) {
      const int i2 = s + ib + j;
      const int i = REV ? (127 - i2) : i2;
      const f32x2 xv = { bf2f_lo(cur[j]), bf2f_hi(cur[j]) };
      h = A2 * h + xv;                            // single v_pk_fma
      *(u32*)(buf + i * 128 + (cb ^ ((u32)((i & 7) << 4)))) = pack2(h.x, h.y);
    }
  }
}

// ---- Carry correction: h_i = l_i + A^{j+1} * C (C folded from chunk-end rows, f32). ----
template <bool REV>
DEVINL void scan_fix(char* buf, int dp, int chunk, f32x2 A2) {
  if (chunk == 0) return;
  f32x2 q = A2;
#pragma unroll
  for (int k = 0; k < 5; ++k) q *= q;            // A^32
  const u32 cb = (u32)(dp * 4);
  f32x2 C = { 0.f, 0.f };
  for (int k = 0; k < chunk; ++k) {
    const int i2 = k * 32 + 31;
    const int i = REV ? (127 - i2) : i2;
    const u32 v = *(const u32*)(buf + i * 128 + (cb ^ ((u32)((i & 7) << 4))));
    const f32x2 xv = { bf2f_lo(v), bf2f_hi(v) };
    C = C * q + xv;
  }
  f32x2 p = A2;
  const int s = chunk * 32;
  u32 nx[8];
#pragma unroll
  for (int j = 0; j < 8; ++j) {
    const int i = REV ? (127 - (s + j)) : (s + j);
    nx[j] = *(const u32*)(buf + i * 128 + (cb ^ ((u32)((i & 7) << 4))));
  }
  for (int ib = 0; ib < 32; ib += 8) {
    u32 cur[8];
#pragma unroll
    for (int j = 0; j < 8; ++j) cur[j] = nx[j];
    if (ib + 8 < 32) {
#pragma unroll
      for (int j = 0; j < 8; ++j) {
        const int i2 = s + ib + 8 + j;
        const int i = REV ? (127 - i2) : i2;
        nx[j] = *(const u32*)(buf + i * 128 + (cb ^ ((u32)((i & 7) << 4))));
      }
    }
#pragma unroll
    for (int j = 0; j < 8; ++j) {
      const int i2 = s + ib + j;
      const int i = REV ? (127 - i2) : i2;
      const f32x2 xv = { bf2f_lo(cur[j]), bf2f_hi(cur[j]) };
      const f32x2 hv = p * C + xv;
      *(u32*)(buf + i * 128 + (cb ^ ((u32)((i & 7) << 4)))) = pack2(hv.x, hv.y);
      p *= A2;
    }
  }
}

// Both scans: dir0 = fwd on bufA, dir1 = rev on bufB; 4 chunks each; 256 threads.
DEVINL void run_scans(char* bufA, char* bufB, int t, int e, const float* __restrict__ A_t) {
  const int dp = t & 31, chunk = (t >> 5) & 3, dir = t >> 7;
  const f32x2 a = *(const f32x2*)(A_t + e * 64 + dp * 2);
  char* sb = dir ? bufB : bufA;
  if (dir == 0) scan_local<false>(sb, dp, chunk, a);
  else          scan_local<true >(sb, dp, chunk, a);
  __syncthreads();
  if (dir == 0) scan_fix<false>(sb, dp, chunk, a);
  else          scan_fix<true >(sb, dp, chunk, a);
}

// acc2 += h @ M[dir] in D[pos][c] orientation (h as A-operand, M as B-operand).
DEVINL void combine64(const char* buf, const u16* __restrict__ Mrow, int dir, int e,
                      int lane, int wv, f32x4v (&acc2)[4][2]) {
  const int l15 = lane & 15, kg = lane >> 4;
#pragma unroll
  for (int ks = 0; ks < 2; ++ks) {
    bf16x8 afr[4], bfr[2];
#pragma unroll
    for (int ct = 0; ct < 4; ++ct)
      afr[ct] = *(const bf16x8*)(Mrow + ((size_t)dir * 64 + ct * 16 + l15) * 128 + e * 64 + ks * 32 + kg * 8);
#pragma unroll
    for (int pt = 0; pt < 2; ++pt) {
      const int row = wv * 32 + pt * 16 + l15;
      bfr[pt] = *(const bf16x8*)(buf + row * 128 + ((u32)(ks * 64 + kg * 16) ^ ((u32)((row & 7) << 4))));
    }
#pragma unroll
    for (int ct = 0; ct < 4; ++ct)
#pragma unroll
      for (int pt = 0; pt < 2; ++pt)
        acc2[ct][pt] = __builtin_amdgcn_mfma_f32_16x16x32_bf16(bfr[pt], afr[ct], acc2[ct][pt], 0, 0, 0);
  }
}

// Store combine acc into smem as f32 [64 c][512B swz rows]; thread's f32x4 is pos-contiguous.
DEVINL void acc_to_outs(const f32x4v (&acc2)[4][2], int lane, int wv, char* buf) {
  const int l15 = lane & 15, kg = lane >> 4;
#pragma unroll
  for (int ct = 0; ct < 4; ++ct)
#pragma unroll
    for (int pt = 0; pt < 2; ++pt) {
      const int c = ct * 16 + l15;
      const int pos = wv * 32 + pt * 16 + kg * 4;
      *(f32x4v*)(buf + c * 512 + ((u32)(pos * 4) ^ ((u32)((c & 7) << 4)))) = acc2[ct][pt];
    }
}

// Epilogue: OutS -> partial [64 c][128 pos] bf16 stream (16 KB).
DEVINL void outs_to_global(const char* buf, u16* __restrict__ og, int t) {
#pragma unroll
  for (int j = 0; j < 16; ++j) {
    const int i = t + j * 256;
    const int c = i >> 6, p2 = (i & 63) * 2;
    const f32x2 v = *(const f32x2*)(buf + c * 512 + ((u32)(p2 * 4) ^ ((u32)((c & 7) << 4))));
    *(u32*)(og + c * 128 + p2) = pack2(v.x, v.y);
  }
}

// ---------------- K_A: x-GEMM (64 d half) + horizontal scans + combine ----------------
// bid = ((b*128)+h)*2+e. Writes x2[bid][w][64] (B-prescaled) and Shp[bid][c][w].
__global__ __launch_bounds__(256, 5) void k_A(
    const float* __restrict__ F_in, const float* __restrict__ prior,
    const u16* __restrict__ Wi_bf, const float* __restrict__ bi,
    const float* __restrict__ Bp, const float* __restrict__ alpha_p,
    const float* __restrict__ A_t, const u16* __restrict__ Mrow,
    u16* __restrict__ x2, u16* __restrict__ Shp) {
  char* bufA = smem;            // 16 KB [128][128B] swz: FT -> Bx -> h_lr
  char* bufB = smem + 16384;    // 16 KB: Bx copy -> h_rl

  const int t = threadIdx.x;
  const int lane = t & 63, wv = t >> 6, l15 = lane & 15, kg = lane >> 4;
  const int bid = blockIdx.x;
  const int b = bid >> 8, h = (bid >> 1) & 127, e = bid & 1;

  // ---- P1: stage Fmod^T bf16 into bufA: row w = 64 c (128B), swz ----
  {
    const int w = t & 127, ch = t >> 7;
    const float alpha = alpha_p[0];
    const float pv = prior[(b * 128 + h) * 128 + w];
    const float* Fb = F_in + ((size_t)b * 64 + ch * 32) * 16384 + h * 128 + w;
    const u32 sw = (u32)((w & 7) << 4);
    char* rowp = bufA + w * 128;
#pragma unroll
    for (int q = 0; q < 4; ++q) {
      float fv[8];
#pragma unroll
      for (int j = 0; j < 8; ++j) fv[j] = fmaf(alpha, pv, Fb[(q * 8 + j) * 16384]);
      uint4 pk;
      pk.x = pack2(fv[0], fv[1]); pk.y = pack2(fv[2], fv[3]);
      pk.z = pack2(fv[4], fv[5]); pk.w = pack2(fv[6], fv[7]);
      *(uint4*)(rowp + ((u32)(ch * 64 + q * 16) ^ sw)) = pk;
    }
  }
  __syncthreads();

  // ---- P2: Fmod B-frags (n=w) into regs before bufA is overwritten ----
  bf16x8 bF[2][2];   // [wj][ks]
#pragma unroll
  for (int wj = 0; wj < 2; ++wj)
#pragma unroll
    for (int ks = 0; ks < 2; ++ks) {
      const int row = wv * 32 + wj * 16 + l15;
      bF[wj][ks] = *(const bf16x8*)(bufA + row * 128 + ((u32)(ks * 64 + kg * 16) ^ ((u32)((row & 7) << 4))));
    }
  __syncthreads();

  // ---- P3: GEMM D[d][w]; prescale by B_d; Bx -> bufA + bufB (8B swizzled) ----
  {
    f32x4v acc[4][2];   // [dt][wj]
#pragma unroll
    for (int dt = 0; dt < 4; ++dt) {
      const f32x4 bv = *(const f32x4*)(bi + e * 64 + dt * 16 + kg * 4);
      const f32x4v bvv = { bv.x, bv.y, bv.z, bv.w };
#pragma unroll
      for (int wj = 0; wj < 2; ++wj) acc[dt][wj] = bvv;
    }
#pragma unroll
    for (int ks = 0; ks < 2; ++ks)
#pragma unroll
      for (int dt = 0; dt < 4; ++dt) {
        const bf16x8 aWi = *(const bf16x8*)(Wi_bf + (e * 64 + dt * 16 + l15) * 64 + ks * 32 + kg * 8);
        acc[dt][0] = __builtin_amdgcn_mfma_f32_16x16x32_bf16(aWi, bF[0][ks], acc[dt][0], 0, 0, 0);
        acc[dt][1] = __builtin_amdgcn_mfma_f32_16x16x32_bf16(aWi, bF[1][ks], acc[dt][1], 0, 0, 0);
      }
#pragma unroll
    for (int dt = 0; dt < 4; ++dt) {
      const f32x4 B4 = *(const f32x4*)(Bp + e * 64 + dt * 16 + kg * 4);
      const f32x4v B4v = { B4.x, B4.y, B4.z, B4.w };
#pragma unroll
      for (int wj = 0; wj < 2; ++wj) {
        const f32x4v sv = acc[dt][wj] * B4v;
        const int w = wv * 32 + wj * 16 + l15;
        const int dl = dt * 16 + kg * 4;          // d_local base
        uint2 pk;
        pk.x = pack2(sv[0], sv[1]);
        pk.y = pack2(sv[2], sv[3]);
        const u32 col = (u32)(dl * 2) ^ ((u32)((w & 7) << 4));
        *(uint2*)(bufA + w * 128 + col) = pk;
        *(uint2*)(bufB + w * 128 + col) = pk;
      }
    }
  }
  barrier_lgkm();   // LDS visible; no global stores outstanding yet

  // ---- P4: Bx -> global x2 (16 KB coalesced stream from bufA) ----
  {
    u16* xg = x2 + (size_t)bid * 8192;
#pragma unroll
    for (int j = 0; j < 4; ++j) {
      const int idx = t + j * 256;
      const int row = idx >> 3, q = idx & 7;
      const uint4 v = *(const uint4*)(bufA + row * 128 + ((u32)(q * 16) ^ ((u32)((row & 7) << 4))));
      *(uint4*)(xg + row * 64 + q * 8) = v;
    }
  }
  // lgkm-only barrier: ds_reads done (data captured in stores), but the 16 KB of
  // global stores keep draining UNDER the scan phase (T4 pattern).
  barrier_lgkm();

  // ---- P5: 4x32 chunked scans (all 256 threads; internal barrier) ----
  run_scans(bufA, bufB, t, e, A_t);
  __syncthreads();

  // ---- P6: combine dir0 (bufA) + dir1 (bufB) ----
  f32x4v acc2[4][2];
#pragma unroll
  for (int i = 0; i < 4; ++i)
#pragma unroll
    for (int j = 0; j < 2; ++j) acc2[i][j] = (f32x4v)0.f;
  combine64(bufA, Mrow, 0, e, lane, wv, acc2);
  combine64(bufB, Mrow, 1, e, lane, wv, acc2);
  __syncthreads();

  // ---- P7: acc -> OutS (32 KB f32 spanning both buffers) ----
  acc_to_outs(acc2, lane, wv, smem);
  __syncthreads();

  // ---- P8: Shp[bid][c][w] (16 KB stream) ----
  outs_to_global(smem, Shp + (size_t)bid * 8192, t);
}

// ---------------- K_B: vertical scans + combine -> Svp[bid][c][h] ----------------
// bid = ((b*128)+w)*2+e.
__global__ __launch_bounds__(256, 5) void k_B(
    const u16* __restrict__ x2,
    const float* __restrict__ A_t, const u16* __restrict__ Mrow,
    u16* __restrict__ Svp) {
  char* bufA = smem;
  char* bufB = smem + 16384;
  const int t = threadIdx.x;
  const int lane = t & 63, wv = t >> 6;
  const int bid = blockIdx.x;
  const int b = bid >> 8, w = (bid >> 1) & 127, e = bid & 1;

  // ---- P1: stage Bx rows (h-major) into both buffers; 128B L3-hot segments ----
#pragma unroll
  for (int j = 0; j < 4; ++j) {
    const int idx = t + j * 256;
    const int hh = idx >> 3, q = idx & 7;
    const uint4 v = *(const uint4*)(x2 + ((size_t)((b * 128 + hh) * 2 + e)) * 8192 + w * 64 + q * 8);
    const u32 col = (u32)(q * 16) ^ ((u32)((hh & 7) << 4));
    *(uint4*)(bufA + hh * 128 + col) = v;
    *(uint4*)(bufB + hh * 128 + col) = v;
  }
  __syncthreads();

  // ---- P2: 4x32 chunked scans ----
  run_scans(bufA, bufB, t, e, A_t);
  __syncthreads();

  // ---- P3: combine dir2 (bufA) + dir3 (bufB) ----
  f32x4v acc2[4][2];
#pragma unroll
  for (int i = 0; i < 4; ++i)
#pragma unroll
    for (int j = 0; j < 2; ++j) acc2[i][j] = (f32x4v)0.f;
  combine64(bufA, Mrow, 2, e, lane, wv, acc2);
  combine64(bufB, Mrow, 3, e, lane, wv, acc2);
  __syncthreads();

  // ---- P4: acc -> OutS ----
  acc_to_outs(acc2, lane, wv, smem);
  __syncthreads();

  // ---- P5: Svp[bid][c][h] (16 KB stream) ----
  outs_to_global(smem, Svp + (size_t)bid * 8192, t);
}

// ---------------- F: out = F_mod + gamma*(Sh0+Sh1 + (Sv0+Sv1)^T + beff) ----------------
__global__ __launch_bounds__(256) void k_final(
    const float* __restrict__ F_in, const float* __restrict__ prior,
    const float* __restrict__ alpha_p, const float* __restrict__ gamma_p,
    const float* __restrict__ beff, const u16* __restrict__ Svp,
    const u16* __restrict__ Shp, float* __restrict__ out) {
  u16* Xu = (u16*)smem;
  const int t = threadIdx.x;
  const int bid = blockIdx.x, b = bid >> 6, c = bid & 63;
  const size_t base = (size_t)bid * 16384;   // (b,c) plane of out/F

  // stage Sv = Svp(e0)+Svp(e1), transposed via LDS: Xu[w][h], stride 132
  for (int i = t; i < 2048; i += 256) {
    const int w = i >> 4, q = i & 15;
    const u16* s0 = Svp + ((size_t)((b * 128 + w) * 2)) * 8192 + c * 128 + q * 8;
    const uint4 a4 = *(const uint4*)(s0);
    const uint4 b4 = *(const uint4*)(s0 + 8192);
    const u16* ap = (const u16*)&a4;
    const u16* bp = (const u16*)&b4;
    u32* dst = (u32*)(Xu + w * 132 + q * 8);
#pragma unroll
    for (int k = 0; k < 4; ++k) {
      const float lo = bf2f(ap[k * 2]) + bf2f(bp[k * 2]);
      const float hi = bf2f(ap[k * 2 + 1]) + bf2f(bp[k * 2 + 1]);
      dst[k] = pack2(lo, hi);
    }
  }
  __syncthreads();
  const float alpha = alpha_p[0], gamma = gamma_p[0];
  const float be = beff[c];
  for (int i = t; i < 2048; i += 256) {
    const int hh = i >> 4, w8 = (i & 15) * 8;
    const size_t off = base + hh * 128 + w8;
    const u16* sh0 = Shp + ((size_t)((b * 128 + hh) * 2)) * 8192 + c * 128 + w8;
    const uint4 g0 = *(const uint4*)(sh0);
    const uint4 g1 = *(const uint4*)(sh0 + 8192);
    const u16* p0 = (const u16*)&g0;
    const u16* p1 = (const u16*)&g1;
    const float* Fp = F_in + off;
    float* Op = out + off;
    const float* Pp = prior + (b * 128 + hh) * 128 + w8;
#pragma unroll
    for (int q = 0; q < 8; ++q) {
      const float sv = bf2f(Xu[(w8 + q) * 132 + hh]);
      Op[q] = Fp[q] + alpha * Pp[q] + gamma * (bf2f(p0[q]) + bf2f(p1[q]) + sv + be);
    }
  }
}

extern "C" void kernel_launch(void* const* d_in, const int* in_sizes, int n_in,
                              void* d_out, int out_size, void* d_ws, size_t ws_size,
                              hipStream_t stream) {
  const float* F_in   = (const float*)d_in[0];
  const float* prior  = (const float*)d_in[1];
  const float* Wi     = (const float*)d_in[2];
  const float* bi     = (const float*)d_in[3];
  const float* A_par  = (const float*)d_in[4];
  const float* B_par  = (const float*)d_in[5];
  const float* alpha  = (const float*)d_in[6];
  const float* gamma  = (const float*)d_in[7];
  const float* Wf     = (const float*)d_in[8];
  const float* bf_    = (const float*)d_in[9];
  const float* Wo     = (const float*)d_in[10];
  const float* bo     = (const float*)d_in[11];
  float* out = (float*)d_out;

  char* ws = (char*)d_ws;
  float* A_t   = (float*)ws;                        // 512 B
  float* beff  = (float*)(ws + 512);                // 256 B
  u16*   Mrow  = (u16*)(ws + 1024);                 // 64 KB: [4][64][128] bf16
  u16*   Wi_bf = (u16*)(ws + 66560);                // 16 KB: [128][64] bf16
  u16*   x2    = (u16*)(ws + 82944);                // 33.5 MB: [2048][128 w][64 d] (B-prescaled)
  u16*   Shp   = (u16*)(ws + 82944 + 33554432);     // 33.5 MB: [2048][64 c][128 w]
  u16*   Svp   = (u16*)(ws + 82944 + 67108864);     // 33.5 MB: [2048][64 c][128 h]

  hipFuncSetAttribute((const void*)k_A, hipFuncAttributeMaxDynamicSharedMemorySize, SCAN_LDS);
  hipFuncSetAttribute((const void*)k_B, hipFuncAttributeMaxDynamicSharedMemorySize, SCAN_LDS);

  k_pre  <<<130, 256, 0, stream>>>(Wf, Wo, bf_, bo, A_par, Wi, A_t, beff, Mrow, Wi_bf);
  k_A    <<<2048, 256, SCAN_LDS, stream>>>(F_in, prior, Wi_bf, bi, B_par, alpha, A_t, Mrow, x2, Shp);
  k_B    <<<2048, 256, SCAN_LDS, stream>>>(x2, A_t, Mrow, Svp);
  k_final<<<512, 256, LDS_X, stream>>>(F_in, prior, alpha, gamma, beff, Svp, Shp, out);
}